// Round 2
// baseline (12071.219 us; speedup 1.0000x reference)
//
#include <hip/hip_runtime.h>

typedef __attribute__((ext_vector_type(8))) short short8;
typedef __attribute__((ext_vector_type(4))) float floatx4;
typedef unsigned short u16;

__device__ __forceinline__ float b2f(u16 s) {
  return __uint_as_float(((unsigned)s) << 16);
}
__device__ __forceinline__ u16 f2b(float f) {
  unsigned u = __float_as_uint(f);
  u = u + 0x7FFFu + ((u >> 16) & 1u);
  return (u16)(u >> 16);
}
__device__ __forceinline__ void atomAddF(float* p, float v) {
  __hip_atomic_fetch_add(p, v, __ATOMIC_RELAXED, __HIP_MEMORY_SCOPE_AGENT);
}

// ---- dtype sniffer: flag=1 if raw float32, flag=0 if bf16 ----
// f32 normal data viewed as u16: mantissa halves hit the Inf/NaN exponent
// pattern (u&0x7F80)==0x7F80 with p~1/256. True bf16 N(0,1) data: never.
__global__ __launch_bounds__(256) void det_k(const u16* __restrict__ x, int n, int* __restrict__ flag) {
  __shared__ int cnt;
  if (threadIdx.x == 0) cnt = 0;
  __syncthreads();
  int c = 0;
  for (int i = threadIdx.x; i < n; i += 256) {
    unsigned u = x[i];
    if ((u & 0x7F80u) == 0x7F80u) c++;
  }
  atomicAdd(&cnt, c);
  __syncthreads();
  if (threadIdx.x == 0) *flag = (cnt > 0) ? 1 : 0;
}

__device__ __forceinline__ u16 ldb16(const void* p, size_t i, int flag) {
  return flag ? f2b(((const float*)p)[i]) : ((const u16*)p)[i];
}
__device__ __forceinline__ float ldf32(const void* p, size_t i, int flag) {
  return flag ? ((const float*)p)[i] : b2f(((const u16*)p)[i]);
}

// ---- input -> canonical bf16 (8 elements/thread) ----
__global__ __launch_bounds__(256) void cvt_k(const void* __restrict__ src, u16* __restrict__ dst,
                                             int n8, const int* __restrict__ flagp) {
  int i = blockIdx.x * 256 + threadIdx.x;
  if (i >= n8) return;
  int flag = *flagp;
  short8 o;
  if (flag) {
    const float* f = (const float*)src + (size_t)i * 8;
#pragma unroll
    for (int j = 0; j < 8; j++) o[j] = (short)f2b(f[j]);
  } else {
    o = ((const short8*)src)[i];
  }
  ((short8*)dst)[i] = o;
}

// ---- canonical bf16 result -> d_out in detected dtype ----
__global__ __launch_bounds__(256) void cvto_k(const u16* __restrict__ oc, const u16* __restrict__ hc,
                                              void* __restrict__ dst, int n, const int* __restrict__ flagp) {
  int i = blockIdx.x * 256 + threadIdx.x;
  if (i >= n) return;
  int flag = *flagp;
  if (flag) {
    ((float*)dst)[i] = b2f(oc[i]);
    ((float*)dst)[(size_t)n + i] = b2f(hc[i]);
  } else {
    ((u16*)dst)[i] = oc[i];
    ((u16*)dst)[(size_t)n + i] = hc[i];
  }
}

// ---------------- fused GEMM: Y = act( (X @ W) * sc + sh ) ----------------
// Wfrag frag-ordered: [K/32][M/16][lane][j], element = W[ks*32+8*(l>>4)+j][ct*16+(l&15)]
// B-fragments read straight from global (weights are L2-resident). No LDS.
template<int K, int M, bool RELU>
__global__ __launch_bounds__(256) void gemm_k(
    const u16* __restrict__ X, int ldx,
    const u16* __restrict__ Wfrag,
    const float* __restrict__ sc, const float* __restrict__ sh,
    u16* __restrict__ Y, int ldy,
    u16* __restrict__ Y2, int ldy2,
    int N)
{
  constexpr int NKS = K / 32, NCT = M / 16;
  const int tid = threadIdx.x;
  const int wid = tid >> 6, l = tid & 63;
  const int lrow = l & 15, lkb = (l >> 4) << 3;
  const int rowbase = blockIdx.x * 128 + wid * 32;

  floatx4 acc[2][NCT];
#pragma unroll
  for (int rt = 0; rt < 2; rt++)
#pragma unroll
    for (int ct = 0; ct < NCT; ct++) acc[rt][ct] = (floatx4){0.f, 0.f, 0.f, 0.f};

  int r0 = rowbase + lrow;      if (r0 >= N) r0 = N - 1;
  int r1 = rowbase + 16 + lrow; if (r1 >= N) r1 = N - 1;
  const u16* x0 = X + (size_t)r0 * ldx + lkb;
  const u16* x1 = X + (size_t)r1 * ldx + lkb;

#pragma unroll
  for (int ks = 0; ks < NKS; ks++) {
    short8 a0 = *(const short8*)(x0 + ks * 32);
    short8 a1 = *(const short8*)(x1 + ks * 32);
#pragma unroll
    for (int ct = 0; ct < NCT; ct++) {
      short8 b = *(const short8*)(Wfrag + ((size_t)(ks * NCT + ct) * 64 + l) * 8);
      acc[0][ct] = __builtin_amdgcn_mfma_f32_16x16x32_bf16(a0, b, acc[0][ct], 0, 0, 0);
      acc[1][ct] = __builtin_amdgcn_mfma_f32_16x16x32_bf16(a1, b, acc[1][ct], 0, 0, 0);
    }
  }

#pragma unroll
  for (int rt = 0; rt < 2; rt++) {
    int rowb = rowbase + rt * 16 + ((l >> 4) << 2);
#pragma unroll
    for (int ct = 0; ct < NCT; ct++) {
      int col = ct * 16 + lrow;
      float s = sc[col], t = sh[col];
#pragma unroll
      for (int r = 0; r < 4; r++) {
        int row = rowb + r;
        if (row < N) {
          float v = acc[rt][ct][r] * s + t;
          if (RELU) v = fmaxf(v, 0.f);
          u16 bv = f2b(v);
          Y[(size_t)row * ldy + col] = bv;
          if (Y2) Y2[(size_t)row * ldy2 + col] = bv;
        }
      }
    }
  }
}

// ---------------- weight frag-reorder (flag-aware loads) ----------------
struct WEnt { const void* W; u16* out; int M; int base; };
struct WPack { WEnt e[10]; int total; };

__global__ __launch_bounds__(256) void wprep_k(WPack p, const int* __restrict__ flagp) {
  int i = blockIdx.x * 256 + threadIdx.x;
  if (i >= p.total) return;
  int flag = *flagp;
  int ei = 0;
  for (int t = 1; t < 10; t++) if (i >= p.e[t].base) ei = t;
  const void* W = p.e[ei].W;
  u16* out = p.e[ei].out;
  int M = p.e[ei].M;
  int lin = i - p.e[ei].base;
  int l = lin & 63, ctks = lin >> 6;
  int NCT = M >> 4;
  int ct = ctks % NCT, ks = ctks / NCT;
  int kb = ks * 32 + ((l >> 4) << 3);
  int m = ct * 16 + (l & 15);
  short8 v;
#pragma unroll
  for (int j = 0; j < 8; j++) v[j] = (short)ldb16(W, (size_t)(kb + j) * M + m, flag);
  *(short8*)(out + (size_t)lin * 8) = v;
}

// ---------------- per-column scale/shift (folds bias + BN) ----------------
struct SEnt { const void* bias; const void* g; const void* b; const void* m; const void* v; int base; };
struct SPack { SEnt e[10]; float* sc; float* sh; int total; };

__global__ __launch_bounds__(256) void sprep_k(SPack p, const int* __restrict__ flagp) {
  int i = blockIdx.x * 256 + threadIdx.x;
  if (i >= p.total) return;
  int flag = *flagp;
  int ei = 0;
  for (int t = 1; t < 10; t++) if (i >= p.e[t].base) ei = t;
  SEnt e = p.e[ei];
  int c = i - e.base;
  float bias = e.bias ? ldf32(e.bias, c, flag) : 0.f;
  float scv = 1.f, shv = bias;
  if (e.g) {
    float s = ldf32(e.g, c, flag) * rsqrtf(ldf32(e.v, c, flag) + 1e-5f);
    scv = s;
    shv = (bias - ldf32(e.m, c, flag)) * s + ldf32(e.b, c, flag);
  }
  p.sc[i] = scv;
  p.sh[i] = shv;
}

// ---------------- degree count (dst side, both graphs) ----------------
__global__ __launch_bounds__(256) void deg_k(const int* __restrict__ dS, const int* __restrict__ dT,
                                             float* __restrict__ degS, float* __restrict__ degT, int E) {
  int stride = gridDim.x * 256;
  for (int i = blockIdx.x * 256 + threadIdx.x; i < E; i += stride) {
    atomAddF(&degS[dS[i]], 1.f);
    atomAddF(&degT[dT[i]], 1.f);
  }
}

__global__ __launch_bounds__(256) void dis_k(float* a, float* b, int N) {
  int i = blockIdx.x * 256 + threadIdx.x;
  if (i < N) { a[i] = rsqrtf(a[i] + 1.f); b[i] = rsqrtf(b[i] + 1.f); }
}

// ---------------- edge scatter: agg[dst] += hW[src] * dis[s]*dis[d] ----------------
__global__ __launch_bounds__(256) void scat_k(const int* __restrict__ src, const int* __restrict__ dst,
                                              const u16* __restrict__ hW, const float* __restrict__ dis,
                                              float* __restrict__ agg, int E) {
  int total = E * 8;
  int stride = gridDim.x * 256;
  for (int g = blockIdx.x * 256 + threadIdx.x; g < total; g += stride) {
    int e = g >> 3, f = (g & 7) << 3;
    int s = src[e], d = dst[e];
    float w = dis[s] * dis[d];
    short8 v = *(const short8*)(hW + (size_t)s * 64 + f);
    float* ap = agg + (size_t)d * 64 + f;
#pragma unroll
    for (int j = 0; j < 8; j++) atomAddF(ap + j, b2f((u16)(unsigned short)v[j]) * w);
  }
}

// ---------------- combine one graph: hsht[:,goff:goff+64] = relu(agg + hW*dis^2 + b) ----------------
__global__ __launch_bounds__(256) void comb_k(const float* __restrict__ agg, const u16* __restrict__ hW,
                                              const float* __restrict__ dis, const void* __restrict__ bias,
                                              u16* __restrict__ hsht, int goff, int N,
                                              const int* __restrict__ flagp) {
  int i = blockIdx.x * 256 + threadIdx.x;
  if (i >= N * 8) return;
  int flag = *flagp;
  int n = i >> 3, f = (i & 7) << 3;
  float d = dis[n], sw = d * d;
  short8 hv = *(const short8*)(hW + (size_t)n * 64 + f);
  short8 o;
#pragma unroll
  for (int j = 0; j < 8; j++) {
    float val = agg[(size_t)n * 64 + f + j] + b2f((u16)(unsigned short)hv[j]) * sw + ldf32(bias, f + j, flag);
    o[j] = (short)f2b(fmaxf(val, 0.f));
  }
  *(short8*)(hsht + (size_t)n * 128 + goff + f) = o;
}

extern "C" void kernel_launch(void* const* d_in, const int* in_sizes, int n_in,
                              void* d_out, int out_size, void* d_ws, size_t ws_size,
                              hipStream_t stream) {
  const int N = in_sizes[0] / 256;
  const int E = in_sizes[2] / 2;
  const void* ctx = d_in[0];
  const void* vis = d_in[1];
  const int* spe = (const int*)d_in[2];
  const int* tre = (const int*)d_in[3];
  (void)n_in; (void)out_size; (void)ws_size;

  char* ws = (char*)d_ws;
  size_t off = 0;
  auto alloc = [&](size_t b) { size_t r = off; off += (b + 255) & ~(size_t)255; return r; };
  const size_t o_agg  = alloc((size_t)N * 64 * 4);   // shared by both graphs (re-zeroed)
  const size_t o_degS = alloc((size_t)N * 4);
  const size_t o_degT = alloc((size_t)N * 4);
  const size_t zspan = off;
  const size_t o_hf  = alloc((size_t)N * 256 * 2);   // [h(64)|c(128)|t(64)]; early: ctx_c
  const size_t o_c1  = alloc((size_t)N * 128 * 2);   // c1 / t1 / hsht
  const size_t o_hWS = alloc((size_t)N * 64 * 2);    // hWS / z2
  const size_t o_hWT = alloc((size_t)N * 64 * 2);    // vis_c / hWT / h_cano
  const size_t o_wf  = alloc((size_t)135168 * 2);
  const size_t o_sc  = alloc((size_t)832 * 4);
  const size_t o_sh  = alloc((size_t)832 * 4);
  const size_t o_fl  = alloc(256);

  float* agg  = (float*)(ws + o_agg);
  float* degS = (float*)(ws + o_degS);
  float* degT = (float*)(ws + o_degT);
  u16* hf  = (u16*)(ws + o_hf);
  u16* ctx_c = hf;
  u16* c1  = (u16*)(ws + o_c1);
  u16* t1 = c1, *hsht = c1;
  u16* hWS = (u16*)(ws + o_hWS);
  u16* hWT = (u16*)(ws + o_hWT);
  u16* vis_c = hWT, *h_cano = hWT;
  u16* wf  = (u16*)(ws + o_wf);
  float* sc = (float*)(ws + o_sc);
  float* sh = (float*)(ws + o_sh);
  int* flagp = (int*)(ws + o_fl);
  u16* z1 = (u16*)(ws + o_agg);       // agg region after GCN done
  u16* z2 = hWS;                      // hWS region after comb
  u16* out_cano = (u16*)(ws + o_agg); // z1 region after head2 consumed it

  // dtype detect + zero accumulators
  det_k<<<1, 256, 0, stream>>>((const u16*)ctx, 65536, flagp);
  hipMemsetAsync(ws + o_agg, 0, zspan, stream);

  // ---- weight frag prep ----
  const int wfoff[10] = {0, 32768, 49152, 53248, 57344, 69632, 81920, 90112, 122880, 131072};
  const int wbase[10] = {0, 4096, 6144, 6656, 7168, 8704, 10240, 11264, 15360, 16384};
  const int wM[10]    = {128, 128, 64, 64, 64, 64, 64, 128, 64, 64};
  const int widx[10]  = {4, 10, 16, 18, 20, 22, 24, 26, 32, 34};
  WPack wp;
  for (int i = 0; i < 10; i++) wp.e[i] = {d_in[widx[i]], wf + (size_t)wfoff[i], wM[i], wbase[i]};
  wp.total = 16896;
  wprep_k<<<(wp.total + 255) / 256, 256, 0, stream>>>(wp, flagp);

  // ---- scale/shift prep ----
  const int sbase[10] = {0, 128, 256, 320, 384, 448, 512, 576, 704, 768};
  const int bidx[10] = {5, 11, 17, 19, -1, -1, 25, 27, 33, 35};
  const int gidx[10] = {6, 12, -1, -1, -1, -1, -1, 28, -1, -1};
  SPack spk;
  for (int i = 0; i < 10; i++) {
    const void* bias = bidx[i] >= 0 ? d_in[bidx[i]] : nullptr;
    const void* g = gidx[i] >= 0 ? d_in[gidx[i]] : nullptr;
    const void* b = gidx[i] >= 0 ? d_in[gidx[i] + 1] : nullptr;
    const void* m = gidx[i] >= 0 ? d_in[gidx[i] + 2] : nullptr;
    const void* v = gidx[i] >= 0 ? d_in[gidx[i] + 3] : nullptr;
    spk.e[i] = {bias, g, b, m, v, sbase[i]};
  }
  spk.sc = sc; spk.sh = sh; spk.total = 832;
  sprep_k<<<4, 256, 0, stream>>>(spk, flagp);

  // ---- canonicalize activations ----
  cvt_k<<<(N * 32 + 255) / 256, 256, 0, stream>>>(ctx, ctx_c, N * 32, flagp);  // N*256/8
  cvt_k<<<(N * 8 + 255) / 256, 256, 0, stream>>>(vis, vis_c, N * 8, flagp);    // N*64/8

  const int G = (N + 127) / 128;
  // ctx tower
  gemm_k<256, 128, true><<<G, 256, 0, stream>>>(ctx_c, 256, wf + wfoff[0], sc + 0,   sh + 0,   c1, 128, (u16*)nullptr, 0, N);
  gemm_k<128, 128, true><<<G, 256, 0, stream>>>(c1, 128,    wf + wfoff[1], sc + 128, sh + 128, hf + 64, 256, (u16*)nullptr, 0, N);
  // tgt tower (t1 overwrites c1 region after it's consumed)
  gemm_k<64, 64, true ><<<G, 256, 0, stream>>>(vis_c, 64,   wf + wfoff[2], sc + 256, sh + 256, t1, 64, (u16*)nullptr, 0, N);
  gemm_k<64, 64, false><<<G, 256, 0, stream>>>(t1, 64,      wf + wfoff[3], sc + 320, sh + 320, hf + 192, 256, (u16*)nullptr, 0, N);
  // GCN linear parts
  gemm_k<192, 64, false><<<G, 256, 0, stream>>>(hf + 64, 256, wf + wfoff[4], sc + 384, sh + 384, hWS, 64, (u16*)nullptr, 0, N);
  gemm_k<192, 64, false><<<G, 256, 0, stream>>>(hf + 64, 256, wf + wfoff[5], sc + 448, sh + 448, hWT, 64, (u16*)nullptr, 0, N);
  // degrees -> dis
  int degB = (E + 255) / 256; if (degB > 2048) degB = 2048;
  deg_k<<<degB, 256, 0, stream>>>(spe + E, tre + E, degS, degT, E);
  dis_k<<<(N + 255) / 256, 256, 0, stream>>>(degS, degT, N);
  // spatial graph
  int scatB = (E * 8 + 255) / 256; if (scatB > 2048) scatB = 2048;
  scat_k<<<scatB, 256, 0, stream>>>(spe, spe + E, hWS, degS, agg, E);
  comb_k<<<(N * 8 + 255) / 256, 256, 0, stream>>>(agg, hWS, degS, d_in[21], hsht, 0, N, flagp);
  // temporal graph (reuse agg)
  hipMemsetAsync(ws + o_agg, 0, (size_t)N * 64 * 4, stream);
  scat_k<<<scatB, 256, 0, stream>>>(tre, tre + E, hWT, degT, agg, E);
  comb_k<<<(N * 8 + 255) / 256, 256, 0, stream>>>(agg, hWT, degT, d_in[23], hsht, 64, N, flagp);
  // fuse -> h (into hf cols 0..63 and canonical h output)
  gemm_k<128, 64, true><<<G, 256, 0, stream>>>(hsht, 128, wf + wfoff[6], sc + 512, sh + 512, hf, 256, h_cano, 64, N);
  // head
  gemm_k<256, 128, true><<<G, 256, 0, stream>>>(hf, 256,  wf + wfoff[7], sc + 576, sh + 576, z1, 128, (u16*)nullptr, 0, N);
  gemm_k<128, 64, true ><<<G, 256, 0, stream>>>(z1, 128,  wf + wfoff[8], sc + 704, sh + 704, z2, 64, (u16*)nullptr, 0, N);
  gemm_k<64, 64, false><<<G, 256, 0, stream>>>(z2, 64,    wf + wfoff[9], sc + 768, sh + 768, out_cano, 64, (u16*)nullptr, 0, N);
  // emit in detected dtype
  cvto_k<<<(N * 64 + 255) / 256, 256, 0, stream>>>(out_cano, h_cano, d_out, N * 64, flagp);
}

// Round 3
// 1051.260 us; speedup vs baseline: 11.4826x; 11.4826x over previous
//
#include <hip/hip_runtime.h>

typedef __attribute__((ext_vector_type(8))) short short8;
typedef __attribute__((ext_vector_type(4))) float floatx4;
typedef unsigned short u16;
typedef unsigned int u32;

__device__ __forceinline__ float b2f(u16 s) {
  return __uint_as_float(((unsigned)s) << 16);
}
__device__ __forceinline__ u16 f2b(float f) {
  unsigned u = __float_as_uint(f);
  u = u + 0x7FFFu + ((u >> 16) & 1u);
  return (u16)(u >> 16);
}

// ---- dtype sniffer: flag=1 if raw float32, flag=0 if bf16 ----
__global__ __launch_bounds__(256) void det_k(const u16* __restrict__ x, int n, int* __restrict__ flag) {
  __shared__ int cnt;
  if (threadIdx.x == 0) cnt = 0;
  __syncthreads();
  int c = 0;
  for (int i = threadIdx.x; i < n; i += 256) {
    unsigned u = x[i];
    if ((u & 0x7F80u) == 0x7F80u) c++;
  }
  atomicAdd(&cnt, c);
  __syncthreads();
  if (threadIdx.x == 0) *flag = (cnt > 0) ? 1 : 0;
}

__device__ __forceinline__ u16 ldb16(const void* p, size_t i, int flag) {
  return flag ? f2b(((const float*)p)[i]) : ((const u16*)p)[i];
}
__device__ __forceinline__ float ldf32(const void* p, size_t i, int flag) {
  return flag ? ((const float*)p)[i] : b2f(((const u16*)p)[i]);
}

// ---- input -> canonical bf16 ----
__global__ __launch_bounds__(256) void cvt_k(const void* __restrict__ src, u16* __restrict__ dst,
                                             int n8, const int* __restrict__ flagp) {
  int i = blockIdx.x * 256 + threadIdx.x;
  if (i >= n8) return;
  int flag = *flagp;
  short8 o;
  if (flag) {
    const float* f = (const float*)src + (size_t)i * 8;
#pragma unroll
    for (int j = 0; j < 8; j++) o[j] = (short)f2b(f[j]);
  } else {
    o = ((const short8*)src)[i];
  }
  ((short8*)dst)[i] = o;
}

// ---- canonical bf16 result -> d_out in detected dtype ----
__global__ __launch_bounds__(256) void cvto_k(const u16* __restrict__ oc, const u16* __restrict__ hc,
                                              void* __restrict__ dst, int n, const int* __restrict__ flagp) {
  int i = blockIdx.x * 256 + threadIdx.x;
  if (i >= n) return;
  int flag = *flagp;
  if (flag) {
    ((float*)dst)[i] = b2f(oc[i]);
    ((float*)dst)[(size_t)n + i] = b2f(hc[i]);
  } else {
    ((u16*)dst)[i] = oc[i];
    ((u16*)dst)[(size_t)n + i] = hc[i];
  }
}

// ---------------- fused GEMM: Y = act( ((X @ W) * sc + sh) * rowsc? ) ----------------
template<int K, int M, bool RELU>
__global__ __launch_bounds__(256) void gemm_k(
    const u16* __restrict__ X, int ldx,
    const u16* __restrict__ Wfrag,
    const float* __restrict__ sc, const float* __restrict__ sh,
    const float* __restrict__ rowsc,
    u16* __restrict__ Y, int ldy,
    u16* __restrict__ Y2, int ldy2,
    int N)
{
  constexpr int NKS = K / 32, NCT = M / 16;
  const int tid = threadIdx.x;
  const int wid = tid >> 6, l = tid & 63;
  const int lrow = l & 15, lkb = (l >> 4) << 3;
  const int rowbase = blockIdx.x * 128 + wid * 32;

  floatx4 acc[2][NCT];
#pragma unroll
  for (int rt = 0; rt < 2; rt++)
#pragma unroll
    for (int ct = 0; ct < NCT; ct++) acc[rt][ct] = (floatx4){0.f, 0.f, 0.f, 0.f};

  int r0 = rowbase + lrow;      if (r0 >= N) r0 = N - 1;
  int r1 = rowbase + 16 + lrow; if (r1 >= N) r1 = N - 1;
  const u16* x0 = X + (size_t)r0 * ldx + lkb;
  const u16* x1 = X + (size_t)r1 * ldx + lkb;

#pragma unroll
  for (int ks = 0; ks < NKS; ks++) {
    short8 a0 = *(const short8*)(x0 + ks * 32);
    short8 a1 = *(const short8*)(x1 + ks * 32);
#pragma unroll
    for (int ct = 0; ct < NCT; ct++) {
      short8 b = *(const short8*)(Wfrag + ((size_t)(ks * NCT + ct) * 64 + l) * 8);
      acc[0][ct] = __builtin_amdgcn_mfma_f32_16x16x32_bf16(a0, b, acc[0][ct], 0, 0, 0);
      acc[1][ct] = __builtin_amdgcn_mfma_f32_16x16x32_bf16(a1, b, acc[1][ct], 0, 0, 0);
    }
  }

#pragma unroll
  for (int rt = 0; rt < 2; rt++) {
    int rowb = rowbase + rt * 16 + ((l >> 4) << 2);
#pragma unroll
    for (int ct = 0; ct < NCT; ct++) {
      int col = ct * 16 + lrow;
      float s = sc[col], t = sh[col];
#pragma unroll
      for (int r = 0; r < 4; r++) {
        int row = rowb + r;
        if (row < N) {
          float v = acc[rt][ct][r] * s + t;
          if (rowsc) v *= rowsc[row];
          if (RELU) v = fmaxf(v, 0.f);
          u16 bv = f2b(v);
          Y[(size_t)row * ldy + col] = bv;
          if (Y2) Y2[(size_t)row * ldy2 + col] = bv;
        }
      }
    }
  }
}

// ---------------- weight frag-reorder ----------------
struct WEnt { const void* W; u16* out; int M; int base; };
struct WPack { WEnt e[10]; int total; };

__global__ __launch_bounds__(256) void wprep_k(WPack p, const int* __restrict__ flagp) {
  int i = blockIdx.x * 256 + threadIdx.x;
  if (i >= p.total) return;
  int flag = *flagp;
  int ei = 0;
  for (int t = 1; t < 10; t++) if (i >= p.e[t].base) ei = t;
  const void* W = p.e[ei].W;
  u16* out = p.e[ei].out;
  int M = p.e[ei].M;
  int lin = i - p.e[ei].base;
  int l = lin & 63, ctks = lin >> 6;
  int NCT = M >> 4;
  int ct = ctks % NCT, ks = ctks / NCT;
  int kb = ks * 32 + ((l >> 4) << 3);
  int m = ct * 16 + (l & 15);
  short8 v;
#pragma unroll
  for (int j = 0; j < 8; j++) v[j] = (short)ldb16(W, (size_t)(kb + j) * M + m, flag);
  *(short8*)(out + (size_t)lin * 8) = v;
}

// ---------------- per-column scale/shift ----------------
struct SEnt { const void* bias; const void* g; const void* b; const void* m; const void* v; int base; };
struct SPack { SEnt e[11]; float* sc; float* sh; int total; };

__global__ __launch_bounds__(256) void sprep_k(SPack p, const int* __restrict__ flagp) {
  int i = blockIdx.x * 256 + threadIdx.x;
  if (i >= p.total) return;
  int flag = *flagp;
  int ei = 0;
  for (int t = 1; t < 11; t++) if (i >= p.e[t].base) ei = t;
  SEnt e = p.e[ei];
  int c = i - e.base;
  float bias = e.bias ? ldf32(e.bias, c, flag) : 0.f;
  float scv = 1.f, shv = bias;
  if (e.g) {
    float s = ldf32(e.g, c, flag) * rsqrtf(ldf32(e.v, c, flag) + 1e-5f);
    scv = s;
    shv = (bias - ldf32(e.m, c, flag)) * s + ldf32(e.b, c, flag);
  }
  p.sc[i] = scv;
  p.sh[i] = shv;
}

// ---------------- CSR build ----------------
__global__ __launch_bounds__(256) void cnt_k(const int* __restrict__ dst, u32* __restrict__ cnt, int E) {
  int stride = gridDim.x * 256;
  for (int i = blockIdx.x * 256 + threadIdx.x; i < E; i += stride)
    atomicAdd(&cnt[dst[i]], 1u);
}

// exclusive scan of cnt[N] -> rowp[N] (partial, per 1024-block) + block sums
__global__ __launch_bounds__(256) void scan1_k(const u32* __restrict__ cnt, int* __restrict__ rowp,
                                               u32* __restrict__ bsum, int N) {
  __shared__ u32 sm[256];
  int t = threadIdx.x;
  int base = blockIdx.x * 1024 + t * 4;
  u32 v0 = 0, v1 = 0, v2 = 0, v3 = 0;
  if (base + 3 < N) {
    uint4 u = *(const uint4*)(cnt + base);
    v0 = u.x; v1 = u.y; v2 = u.z; v3 = u.w;
  } else {
    if (base + 0 < N) v0 = cnt[base + 0];
    if (base + 1 < N) v1 = cnt[base + 1];
    if (base + 2 < N) v2 = cnt[base + 2];
  }
  u32 tsum = v0 + v1 + v2 + v3;
  u32 x = tsum;
  sm[t] = x;
  for (int o = 1; o < 256; o <<= 1) {
    __syncthreads();
    u32 y = (t >= o) ? sm[t - o] : 0u;
    __syncthreads();
    x += y;
    sm[t] = x;
  }
  u32 ex = x - tsum;
  if (base + 0 < N) rowp[base + 0] = (int)ex;
  if (base + 1 < N) rowp[base + 1] = (int)(ex + v0);
  if (base + 2 < N) rowp[base + 2] = (int)(ex + v0 + v1);
  if (base + 3 < N) rowp[base + 3] = (int)(ex + v0 + v1 + v2);
  if (t == 255) bsum[blockIdx.x] = x;
}

__global__ __launch_bounds__(256) void scan2_k(u32* __restrict__ bsum, int nb, int* __restrict__ rowp, int N) {
  __shared__ u32 sm[256];
  int t = threadIdx.x;
  u32 v = (t < nb) ? bsum[t] : 0u;
  u32 x = v;
  sm[t] = x;
  for (int o = 1; o < 256; o <<= 1) {
    __syncthreads();
    u32 y = (t >= o) ? sm[t - o] : 0u;
    __syncthreads();
    x += y;
    sm[t] = x;
  }
  if (t < nb) bsum[t] = x - v;
  if (t == 255) rowp[N] = (int)x;   // == E
}

__global__ __launch_bounds__(256) void scan3_k(int* __restrict__ rowp, const u32* __restrict__ bsum, int N) {
  int t = threadIdx.x, base = blockIdx.x * 1024 + t * 4;
  u32 add = bsum[blockIdx.x];
#pragma unroll
  for (int j = 0; j < 4; j++) {
    int i = base + j;
    if (i < N) rowp[i] += (int)add;
  }
}

__global__ __launch_bounds__(256) void disn_k(const u32* __restrict__ cnt, float* __restrict__ dis, int N) {
  int i = blockIdx.x * 256 + threadIdx.x;
  if (i < N) dis[i] = rsqrtf((float)cnt[i] + 1.f);
}

// bucket-fill: consumes cnt back to zero via atomicSub
__global__ __launch_bounds__(256) void fill_k(const int* __restrict__ src, const int* __restrict__ dst,
                                              u32* __restrict__ cnt, const int* __restrict__ rowp,
                                              int* __restrict__ csr, int E) {
  int stride = gridDim.x * 256;
  for (int i = blockIdx.x * 256 + threadIdx.x; i < E; i += stride) {
    int d = dst[i];
    u32 pos = atomicSub(&cnt[d], 1u) - 1u;
    csr[rowp[d] + (int)pos] = src[i];
  }
}

// ---------------- gather-side SpMM: one wave per node, lane = feature ----------------
// out_col = relu( dis[n] * (sum_e hWd[src_e] + hWd[n]) + bias )
__global__ __launch_bounds__(256) void spmm_k(const int* __restrict__ csr, const int* __restrict__ rowp,
                                              const u16* __restrict__ hWd, const float* __restrict__ dis,
                                              const float* __restrict__ biasf,
                                              u16* __restrict__ hsht, int goff, int N) {
  int n = (blockIdx.x * 256 + threadIdx.x) >> 6;
  int lane = threadIdx.x & 63;
  if (n >= N) return;
  int base = rowp[n], end = rowp[n + 1];
  float acc = 0.f;
  for (int off = base; off < end; off += 64) {
    int m = end - off;
    if (m > 64) m = 64;
    int eid = 0;
    if (lane < m) eid = csr[off + lane];
    int j = 0;
    for (; j + 4 <= m; j += 4) {
      int s0 = __builtin_amdgcn_readlane(eid, j);
      int s1 = __builtin_amdgcn_readlane(eid, j + 1);
      int s2 = __builtin_amdgcn_readlane(eid, j + 2);
      int s3 = __builtin_amdgcn_readlane(eid, j + 3);
      float a0 = b2f(hWd[(size_t)s0 * 64 + lane]);
      float a1 = b2f(hWd[(size_t)s1 * 64 + lane]);
      float a2 = b2f(hWd[(size_t)s2 * 64 + lane]);
      float a3 = b2f(hWd[(size_t)s3 * 64 + lane]);
      acc += (a0 + a1) + (a2 + a3);
    }
    for (; j < m; j++) {
      int s0 = __builtin_amdgcn_readlane(eid, j);
      acc += b2f(hWd[(size_t)s0 * 64 + lane]);
    }
  }
  float v = dis[n] * (acc + b2f(hWd[(size_t)n * 64 + lane])) + biasf[lane];
  v = fmaxf(v, 0.f);
  hsht[(size_t)n * 128 + goff + lane] = f2b(v);
}

extern "C" void kernel_launch(void* const* d_in, const int* in_sizes, int n_in,
                              void* d_out, int out_size, void* d_ws, size_t ws_size,
                              hipStream_t stream) {
  const int N = in_sizes[0] / 256;
  const int E = in_sizes[2] / 2;
  const void* ctx = d_in[0];
  const void* vis = d_in[1];
  const int* spe = (const int*)d_in[2];
  const int* tre = (const int*)d_in[3];
  (void)n_in; (void)out_size; (void)ws_size;

  char* ws = (char*)d_ws;
  size_t off = 0;
  auto alloc = [&](size_t b) { size_t r = off; off += (b + 255) & ~(size_t)255; return r; };
  const size_t o_cnt  = alloc((size_t)N * 4);          // zeroed; self-restoring
  const size_t o_rowS = alloc((size_t)(N + 1) * 4);
  const size_t o_rowT = alloc((size_t)(N + 1) * 4);
  const size_t o_csr  = alloc((size_t)E * 4);          // shared S then T; later z2
  const size_t o_disS = alloc((size_t)N * 4);
  const size_t o_disT = alloc((size_t)N * 4);
  const size_t o_bsum = alloc(1024);
  const size_t o_hf   = alloc((size_t)N * 256 * 2);    // [h|c|t]; early: ctx_c
  const size_t o_c1   = alloc((size_t)N * 128 * 2);    // c1/t1/hsht/z1
  const size_t o_hWdS = alloc((size_t)N * 64 * 2);     // hWdS; later out_cano
  const size_t o_hWdT = alloc((size_t)N * 64 * 2);     // vis_c; hWdT; later h_cano
  const size_t o_wf   = alloc((size_t)135168 * 2);
  const size_t o_sc   = alloc((size_t)896 * 4);
  const size_t o_sh   = alloc((size_t)896 * 4);
  const size_t o_fl   = alloc(256);

  u32* cnt   = (u32*)(ws + o_cnt);
  int* rowS  = (int*)(ws + o_rowS);
  int* rowT  = (int*)(ws + o_rowT);
  int* csr   = (int*)(ws + o_csr);
  float* disS = (float*)(ws + o_disS);
  float* disT = (float*)(ws + o_disT);
  u32* bsum  = (u32*)(ws + o_bsum);
  u16* hf    = (u16*)(ws + o_hf);
  u16* ctx_c = hf;
  u16* c1    = (u16*)(ws + o_c1);
  u16* t1 = c1, *hsht = c1, *z1 = c1;
  u16* hWdS  = (u16*)(ws + o_hWdS);
  u16* hWdT  = (u16*)(ws + o_hWdT);
  u16* vis_c = hWdT, *h_cano = hWdT;
  u16* wf    = (u16*)(ws + o_wf);
  float* sc  = (float*)(ws + o_sc);
  float* sh  = (float*)(ws + o_sh);
  int* flagp = (int*)(ws + o_fl);
  u16* z2 = (u16*)(ws + o_csr);
  u16* out_cano = hWdS;

  det_k<<<1, 256, 0, stream>>>((const u16*)ctx, 65536, flagp);
  hipMemsetAsync(ws + o_cnt, 0, (size_t)N * 4, stream);

  // ---- weight frag prep ----
  const int wfoff[10] = {0, 32768, 49152, 53248, 57344, 69632, 81920, 90112, 122880, 131072};
  const int wbase[10] = {0, 4096, 6144, 6656, 7168, 8704, 10240, 11264, 15360, 16384};
  const int wM[10]    = {128, 128, 64, 64, 64, 64, 64, 128, 64, 64};
  const int widx[10]  = {4, 10, 16, 18, 20, 22, 24, 26, 32, 34};
  WPack wp;
  for (int i = 0; i < 10; i++) wp.e[i] = {d_in[widx[i]], wf + (size_t)wfoff[i], wM[i], wbase[i]};
  wp.total = 16896;
  wprep_k<<<(wp.total + 255) / 256, 256, 0, stream>>>(wp, flagp);

  // ---- scale/shift prep (11: last is identity for GCN gemms) ----
  const int sbase[11] = {0, 128, 256, 320, 384, 448, 512, 576, 704, 768, 832};
  const int bidx[11] = {5, 11, 17, 19, 21, 23, 25, 27, 33, 35, -1};
  const int gidx[11] = {6, 12, -1, -1, -1, -1, -1, 28, -1, -1, -1};
  SPack spk;
  for (int i = 0; i < 11; i++) {
    const void* bias = bidx[i] >= 0 ? d_in[bidx[i]] : nullptr;
    const void* g = gidx[i] >= 0 ? d_in[gidx[i]] : nullptr;
    const void* b = gidx[i] >= 0 ? d_in[gidx[i] + 1] : nullptr;
    const void* m = gidx[i] >= 0 ? d_in[gidx[i] + 2] : nullptr;
    const void* v = gidx[i] >= 0 ? d_in[gidx[i] + 3] : nullptr;
    spk.e[i] = {bias, g, b, m, v, sbase[i]};
  }
  spk.sc = sc; spk.sh = sh; spk.total = 896;
  sprep_k<<<4, 256, 0, stream>>>(spk, flagp);

  // ---- canonicalize activations ----
  cvt_k<<<(N * 32 + 255) / 256, 256, 0, stream>>>(ctx, ctx_c, N * 32, flagp);
  cvt_k<<<(N * 8 + 255) / 256, 256, 0, stream>>>(vis, vis_c, N * 8, flagp);

  // ---- CSR builds ----
  int eB = (E + 255) / 256; if (eB > 2048) eB = 2048;
  const int nb = (N + 1023) / 1024;
  // S
  cnt_k<<<eB, 256, 0, stream>>>(spe + E, cnt, E);
  scan1_k<<<nb, 256, 0, stream>>>(cnt, rowS, bsum, N);
  scan2_k<<<1, 256, 0, stream>>>(bsum, nb, rowS, N);
  scan3_k<<<nb, 256, 0, stream>>>(rowS, bsum, N);
  disn_k<<<(N + 255) / 256, 256, 0, stream>>>(cnt, disS, N);
  fill_k<<<eB, 256, 0, stream>>>(spe, spe + E, cnt, rowS, csr, E);   // cnt -> 0
  // T (counts only; fill deferred until csr free after spmmS)
  cnt_k<<<eB, 256, 0, stream>>>(tre + E, cnt, E);
  scan1_k<<<nb, 256, 0, stream>>>(cnt, rowT, bsum, N);
  scan2_k<<<1, 256, 0, stream>>>(bsum, nb, rowT, N);
  scan3_k<<<nb, 256, 0, stream>>>(rowT, bsum, N);
  disn_k<<<(N + 255) / 256, 256, 0, stream>>>(cnt, disT, N);

  const int G = (N + 127) / 128;
  // ctx tower
  gemm_k<256, 128, true><<<G, 256, 0, stream>>>(ctx_c, 256, wf + wfoff[0], sc + 0,   sh + 0,   nullptr, c1, 128, (u16*)nullptr, 0, N);
  gemm_k<128, 128, true><<<G, 256, 0, stream>>>(c1, 128,    wf + wfoff[1], sc + 128, sh + 128, nullptr, hf + 64, 256, (u16*)nullptr, 0, N);
  // tgt tower
  gemm_k<64, 64, true ><<<G, 256, 0, stream>>>(vis_c, 64,   wf + wfoff[2], sc + 256, sh + 256, nullptr, t1, 64, (u16*)nullptr, 0, N);
  gemm_k<64, 64, false><<<G, 256, 0, stream>>>(t1, 64,      wf + wfoff[3], sc + 320, sh + 320, nullptr, hf + 192, 256, (u16*)nullptr, 0, N);
  // GCN linear parts, row-scaled by dis: hWd = (fus @ W) * dis[row]
  gemm_k<192, 64, false><<<G, 256, 0, stream>>>(hf + 64, 256, wf + wfoff[4], sc + 832, sh + 832, disS, hWdS, 64, (u16*)nullptr, 0, N);
  gemm_k<192, 64, false><<<G, 256, 0, stream>>>(hf + 64, 256, wf + wfoff[5], sc + 832, sh + 832, disT, hWdT, 64, (u16*)nullptr, 0, N);
  // spatial aggregation
  spmm_k<<<(N + 3) / 4, 256, 0, stream>>>(csr, rowS, hWdS, disS, sh + 384, hsht, 0, N);
  // temporal fill + aggregation (csr reused)
  fill_k<<<eB, 256, 0, stream>>>(tre, tre + E, cnt, rowT, csr, E);   // cnt -> 0
  spmm_k<<<(N + 3) / 4, 256, 0, stream>>>(csr, rowT, hWdT, disT, sh + 448, hsht, 64, N);
  // fuse -> h
  gemm_k<128, 64, true><<<G, 256, 0, stream>>>(hsht, 128, wf + wfoff[6], sc + 512, sh + 512, nullptr, hf, 256, h_cano, 64, N);
  // head
  gemm_k<256, 128, true><<<G, 256, 0, stream>>>(hf, 256,  wf + wfoff[7], sc + 576, sh + 576, nullptr, z1, 128, (u16*)nullptr, 0, N);
  gemm_k<128, 64, true ><<<G, 256, 0, stream>>>(z1, 128,  wf + wfoff[8], sc + 704, sh + 704, nullptr, z2, 64, (u16*)nullptr, 0, N);
  gemm_k<64, 64, false><<<G, 256, 0, stream>>>(z2, 64,    wf + wfoff[9], sc + 768, sh + 768, nullptr, out_cano, 64, (u16*)nullptr, 0, N);
  // emit in detected dtype
  cvto_k<<<(N * 64 + 255) / 256, 256, 0, stream>>>(out_cano, h_cano, d_out, N * 64, flagp);
}